// Round 7
// baseline (100.203 us; speedup 1.0000x reference)
//
#include <hip/hip_runtime.h>
#include <math.h>

#define NROWS 65536
#define D 64
#define K 1024
#define BR 64             // rows per block: w0,w1 = rows 0-31 (code halves 0/1); w2,w3 = rows 32-63
#define THREADS 256
#define TAU_S 0.005f      // certification gap in s-units (dist gap = 2x)
#define LOSS_SCALE (1.25f / (65536.0f * 64.0f))

typedef short bf16x8 __attribute__((ext_vector_type(8)));
typedef float f32x4 __attribute__((ext_vector_type(4)));

__device__ inline unsigned short f2bf(float f) {
    unsigned int u = __float_as_uint(f);
    unsigned int r = u + 0x7fffu + ((u >> 16) & 1u);   // RN-even
    return (unsigned short)(r >> 16);
}
__device__ inline float bf2f(unsigned short h) {
    return __uint_as_float(((unsigned int)h) << 16);
}
__device__ inline void cvt8(const float4& a, const float4& b, bf16x8& h, bf16x8& l) {
    float f[8] = {a.x, a.y, a.z, a.w, b.x, b.y, b.z, b.w};
#pragma unroll
    for (int j = 0; j < 8; ++j) {
        unsigned short hb = f2bf(f[j]);
        h[j] = (short)hb;
        l[j] = (short)f2bf(f[j] - bf2f(hb));
    }
}

#define MFMA __builtin_amdgcn_mfma_f32_16x16x32_bf16

// prep: half-norms Ch + E limbs in MFMA FRAGMENT order + zero loss.
// Fragment (ct, kt, limb): 64 lanes; lane l holds code ct*16+(l&15),
// dims [kt*32 + (l>>4)*8, +8).  Eswz index = (ct*4 + kt*2 + limb)*64 + lane.
__global__ void vq_prep(const float* __restrict__ E, float* __restrict__ Ch,
                        bf16x8* __restrict__ Eswz, float* __restrict__ lossp) {
    int k = blockIdx.x * blockDim.x + threadIdx.x;
    if (k == 0) *lossp = 0.f;
    if (k >= K) return;
    const float4* ev = (const float4*)(E + (size_t)k * D);
    float4 v4[16];
    float s = 0.f;
#pragma unroll
    for (int p = 0; p < 16; ++p) {
        float4 v = ev[p];
        v4[p] = v;
        s = fmaf(v.x, v.x, s); s = fmaf(v.y, v.y, s);
        s = fmaf(v.z, v.z, s); s = fmaf(v.w, v.w, s);
    }
    Ch[k] = 0.5f * s;
    int ct = k >> 4, li = k & 15;
#pragma unroll
    for (int kt = 0; kt < 2; ++kt)
#pragma unroll
        for (int o = 0; o < 4; ++o) {
            int lane = li + 16 * o;
            bf16x8 h, l;
            cvt8(v4[kt * 8 + o * 2], v4[kt * 8 + o * 2 + 1], h, l);
            Eswz[(size_t)(ct * 4 + kt * 2 + 0) * 64 + lane] = h;
            Eswz[(size_t)(ct * 4 + kt * 2 + 1) * 64 + lane] = l;
        }
}

__global__ __launch_bounds__(THREADS, 4) void vq_main(
    const float* __restrict__ X, const float* __restrict__ E,
    const float* __restrict__ Chg, const bf16x8* __restrict__ Eswz,
    float* __restrict__ out, float* __restrict__ lossp)
{
    __shared__ float sM[2][BR], sM2[2][BR];
    __shared__ int   sK[2][BR];
    __shared__ int   sIdx[BR], sFlag[BR];
    __shared__ int   sNf;

    const int t    = threadIdx.x;
    const int w    = t >> 6;
    const int lane = t & 63;
    const int l15  = lane & 15;
    const int l4   = lane >> 4;
    const int rg   = w >> 1;           // row group (0: rows 0-31, 1: rows 32-63)
    const int half = w & 1;            // code half (0: codes 0-511, 1: 512-1023)

    if (t == 0) sNf = 0;

    const float4* Xg4 = (const float4*)X;
    const float4* Eg4 = (const float4*)E;

    // ---- A fragments: 32 rows/wave, straight from global ----
    bf16x8 ah[2][2], al[2][2];
#pragma unroll
    for (int rt = 0; rt < 2; ++rt) {
        size_t ab = ((size_t)blockIdx.x * BR + rg * 32 + rt * 16 + l15) * 16;
#pragma unroll
        for (int kt = 0; kt < 2; ++kt) {
            float4 fa = Xg4[ab + kt * 8 + l4 * 2];
            float4 fb = Xg4[ab + kt * 8 + l4 * 2 + 1];
            cvt8(fa, fb, ah[rt][kt], al[rt][kt]);
        }
    }

    float m[2][4], m2[2][4]; int bk[2][4];
#pragma unroll
    for (int rt = 0; rt < 2; ++rt)
#pragma unroll
        for (int r = 0; r < 4; ++r) { m[rt][r] = -INFINITY; m2[rt][r] = -INFINITY; bk[rt][r] = 0; }

    const int ctbase = half * 32;      // 16-code tiles 32*half .. +32

    // ---- main loop: no LDS, no barriers; B frags direct from L1/L2 ----
#pragma unroll 2
    for (int g = 0; g < 16; ++g) {
        const int ct0 = ctbase + g * 2;
        const int ct1 = ct0 + 1;
        const bf16x8* B0 = Eswz + (size_t)ct0 * 256 + lane;
        const bf16x8* B1 = Eswz + (size_t)ct1 * 256 + lane;
        bf16x8 bh00 = B0[0],   bl00 = B0[64];
        bf16x8 bh01 = B0[128], bl01 = B0[192];
        bf16x8 bh10 = B1[0],   bl10 = B1[64];
        bf16x8 bh11 = B1[128], bl11 = B1[192];
        float ce0 = Chg[ct0 * 16 + l15];
        float ce1 = Chg[ct1 * 16 + l15];

        f32x4 a00 = {-ce0, -ce0, -ce0, -ce0};
        f32x4 a01 = {-ce0, -ce0, -ce0, -ce0};
        f32x4 a10 = {-ce1, -ce1, -ce1, -ce1};
        f32x4 a11 = {-ce1, -ce1, -ce1, -ce1};

        a00 = MFMA(ah[0][0], bh00, a00, 0, 0, 0); a01 = MFMA(ah[1][0], bh00, a01, 0, 0, 0);
        a10 = MFMA(ah[0][0], bh10, a10, 0, 0, 0); a11 = MFMA(ah[1][0], bh10, a11, 0, 0, 0);
        a00 = MFMA(ah[0][1], bh01, a00, 0, 0, 0); a01 = MFMA(ah[1][1], bh01, a01, 0, 0, 0);
        a10 = MFMA(ah[0][1], bh11, a10, 0, 0, 0); a11 = MFMA(ah[1][1], bh11, a11, 0, 0, 0);
        a00 = MFMA(al[0][0], bh00, a00, 0, 0, 0); a01 = MFMA(al[1][0], bh00, a01, 0, 0, 0);
        a10 = MFMA(al[0][0], bh10, a10, 0, 0, 0); a11 = MFMA(al[1][0], bh10, a11, 0, 0, 0);
        a00 = MFMA(al[0][1], bh01, a00, 0, 0, 0); a01 = MFMA(al[1][1], bh01, a01, 0, 0, 0);
        a10 = MFMA(al[0][1], bh11, a10, 0, 0, 0); a11 = MFMA(al[1][1], bh11, a11, 0, 0, 0);
        a00 = MFMA(ah[0][0], bl00, a00, 0, 0, 0); a01 = MFMA(ah[1][0], bl00, a01, 0, 0, 0);
        a10 = MFMA(ah[0][0], bl10, a10, 0, 0, 0); a11 = MFMA(ah[1][0], bl10, a11, 0, 0, 0);
        a00 = MFMA(ah[0][1], bl01, a00, 0, 0, 0); a01 = MFMA(ah[1][1], bl01, a01, 0, 0, 0);
        a10 = MFMA(ah[0][1], bl11, a10, 0, 0, 0); a11 = MFMA(ah[1][1], bl11, a11, 0, 0, 0);

        const int k0 = ct0 * 16 + l15;
        const int k1 = ct1 * 16 + l15;
#pragma unroll
        for (int r = 0; r < 4; ++r) {
            float v;
            v = a00[r];
            m2[0][r] = fmaxf(m2[0][r], fminf(m[0][r], v));
            bk[0][r] = (v > m[0][r]) ? k0 : bk[0][r];
            m[0][r]  = fmaxf(m[0][r], v);
            v = a01[r];
            m2[1][r] = fmaxf(m2[1][r], fminf(m[1][r], v));
            bk[1][r] = (v > m[1][r]) ? k0 : bk[1][r];
            m[1][r]  = fmaxf(m[1][r], v);
            v = a10[r];
            m2[0][r] = fmaxf(m2[0][r], fminf(m[0][r], v));
            bk[0][r] = (v > m[0][r]) ? k1 : bk[0][r];
            m[0][r]  = fmaxf(m[0][r], v);
            v = a11[r];
            m2[1][r] = fmaxf(m2[1][r], fminf(m[1][r], v));
            bk[1][r] = (v > m[1][r]) ? k1 : bk[1][r];
            m[1][r]  = fmaxf(m[1][r], v);
        }
    }

    // ---- per-row top2 reduce across 16 col-lanes, stash per code-half ----
#pragma unroll
    for (int rt = 0; rt < 2; ++rt)
#pragma unroll
        for (int r = 0; r < 4; ++r) {
            float mm = m[rt][r], mm2 = m2[rt][r]; int kk = bk[rt][r];
#pragma unroll
            for (int off = 1; off < 16; off <<= 1) {
                float om  = __shfl_xor(mm,  off, 64);
                float om2 = __shfl_xor(mm2, off, 64);
                int   ok  = __shfl_xor(kk,  off, 64);
                mm2 = fmaxf(fmaxf(mm2, om2), fminf(mm, om));
                if (om > mm || (om == mm && ok < kk)) { mm = om; kk = ok; }
            }
            if (l15 == 0) {
                int lr = rg * 32 + rt * 16 + l4 * 4 + r;
                sM[half][lr] = mm; sM2[half][lr] = mm2; sK[half][lr] = kk;
            }
        }
    __syncthreads();

    // ---- combine code halves (one thread per row) ----
    if (t < BR) {
        float mA = sM[0][t], mB = sM[1][t];
        int   kA = sK[0][t], kB = sK[1][t];
        float top = fmaxf(mA, mB);
        int   kk  = (mB > mA) ? kB : kA;          // tie -> half A (lower codes)
        float sec = fmaxf(fmaxf(sM2[0][t], sM2[1][t]), fminf(mA, mB));
        sIdx[t] = kk;
        if (top - sec < TAU_S) {
            int pos = atomicAdd(&sNf, 1);
            sFlag[pos] = t;
        }
    }
    __syncthreads();

    // ---- fused exact fp32 re-rank of flagged rows (one wave per row) ----
    {
        int nf = sNf;
        for (int i = w; i < nf; i += 4) {
            int lr = sFlag[i];
            size_t grow = (size_t)blockIdx.x * BR + lr;
            const float4* xr = Xg4 + grow * 16;
            float bs = -INFINITY; int bki = 0;
#pragma unroll 1
            for (int jj = 0; jj < 16; ++jj) {
                int kq = jj * 64 + lane;
                const float4* er = Eg4 + (size_t)kq * 16;
                float a0 = 0.f, a1 = 0.f, a2 = 0.f, a3 = 0.f;
#pragma unroll
                for (int p = 0; p < 16; p += 4) {
                    float4 xv0 = xr[p],     e0 = er[p];
                    float4 xv1 = xr[p + 1], e1 = er[p + 1];
                    float4 xv2 = xr[p + 2], e2 = er[p + 2];
                    float4 xv3 = xr[p + 3], e3 = er[p + 3];
                    a0 = fmaf(xv0.x, e0.x, a0); a0 = fmaf(xv0.y, e0.y, a0);
                    a0 = fmaf(xv0.z, e0.z, a0); a0 = fmaf(xv0.w, e0.w, a0);
                    a1 = fmaf(xv1.x, e1.x, a1); a1 = fmaf(xv1.y, e1.y, a1);
                    a1 = fmaf(xv1.z, e1.z, a1); a1 = fmaf(xv1.w, e1.w, a1);
                    a2 = fmaf(xv2.x, e2.x, a2); a2 = fmaf(xv2.y, e2.y, a2);
                    a2 = fmaf(xv2.z, e2.z, a2); a2 = fmaf(xv2.w, e2.w, a2);
                    a3 = fmaf(xv3.x, e3.x, a3); a3 = fmaf(xv3.y, e3.y, a3);
                    a3 = fmaf(xv3.z, e3.z, a3); a3 = fmaf(xv3.w, e3.w, a3);
                }
                float sv = ((a0 + a1) + (a2 + a3)) - Chg[kq];
                if (sv > bs) { bs = sv; bki = kq; }
            }
#pragma unroll
            for (int off = 1; off < 64; off <<= 1) {
                float ob = __shfl_xor(bs, off, 64);
                int  okk = __shfl_xor(bki, off, 64);
                if (ob > bs || (ob == bs && okk < bki)) { bs = ob; bki = okk; }
            }
            if (lane == 0) sIdx[lr] = bki;
        }
    }
    __syncthreads();

    // ---- output gather + loss (4 threads per row) ----
    {
        int row = t >> 2, q = t & 3;
        int kb = sIdx[row];
        size_t grow = (size_t)blockIdx.x * BR + row;
        const float4* eq   = Eg4 + (size_t)kb * 16;
        const float4* xrow = Xg4 + grow * 16;
        float4* orow = (float4*)out + grow * 16;
        float ls = 0.f;
#pragma unroll
        for (int j = 0; j < 4; ++j) {
            int u = q * 4 + j;
            float4 qv = eq[u];
            float4 xv = xrow[u];
            orow[u] = qv;
            float dx = qv.x - xv.x; ls = fmaf(dx, dx, ls);
            float dy = qv.y - xv.y; ls = fmaf(dy, dy, ls);
            float dz = qv.z - xv.z; ls = fmaf(dz, dz, ls);
            float dw = qv.w - xv.w; ls = fmaf(dw, dw, ls);
        }
#pragma unroll
        for (int off = 32; off > 0; off >>= 1) ls += __shfl_down(ls, off, 64);
        if (lane == 0) atomicAdd(lossp, ls * LOSS_SCALE);
    }
}

extern "C" void kernel_launch(void* const* d_in, const int* in_sizes, int n_in,
                              void* d_out, int out_size, void* d_ws, size_t ws_size,
                              hipStream_t stream) {
    const float* X = (const float*)d_in[0];        // [64,1024,64] f32
    const float* E = (const float*)d_in[1];        // [1024,64] f32
    float* out   = (float*)d_out;
    float* lossp = out + (size_t)NROWS * D;

    // ws layout (4-byte units): Ch[1024], then Eswz (16384 bf16x8 = 256 KB)
    float*  Ch   = (float*)d_ws;
    bf16x8* Eswz = (bf16x8*)((float*)d_ws + 1024);

    vq_prep<<<(K + 255) / 256, 256, 0, stream>>>(E, Ch, Eswz, lossp);

    vq_main<<<NROWS / BR, THREADS, 0, stream>>>(
        X, E, Ch, Eswz, out, lossp);
}